// Round 5
// baseline (1233.371 us; speedup 1.0000x reference)
//
#include <hip/hip_runtime.h>
#include <hip/hip_bf16.h>

#define NBOX  380
#define NLOCS 85
#define NINST 340   // B(4) * NLOCS(85)
#define NBLK  768
#define GOLDEN 0x600DF00Du

// box index -> location index (from _recon_indices structure)
__device__ __forceinline__ int loc_of_box(int n) {
    if (n < 256) return n >> 2;               // fm=8, 4 boxes/loc
    if (n < 352) return 64 + (n - 256) / 6;   // fm=4, 6 boxes/loc
    if (n < 376) return 80 + (n - 352) / 6;   // fm=2, 6 boxes/loc
    return 84;                                // fm=1, 4 boxes/loc
}

// Self-resetting grid barrier: counter resets via last-arriver, generation is
// monotonic (never reset -> poison-proof across graph replays).
__device__ __forceinline__ void grid_bar(int* cnt, unsigned* gen) {
    __syncthreads();
    if (threadIdx.x == 0) {
        __threadfence();   // release: push this block's stores past L2 (wbl2)
        unsigned g0 = __hip_atomic_load(gen, __ATOMIC_SEQ_CST, __HIP_MEMORY_SCOPE_AGENT);
        int old = __hip_atomic_fetch_add(cnt, 1, __ATOMIC_SEQ_CST, __HIP_MEMORY_SCOPE_AGENT);
        if (old == NBLK - 1) {
            __hip_atomic_store(cnt, 0, __ATOMIC_RELAXED, __HIP_MEMORY_SCOPE_AGENT);
            __hip_atomic_fetch_add(gen, 1u, __ATOMIC_SEQ_CST, __HIP_MEMORY_SCOPE_AGENT);
        } else {
            while (__hip_atomic_load(gen, __ATOMIC_SEQ_CST, __HIP_MEMORY_SCOPE_AGENT) == g0) {
                __builtin_amdgcn_s_sleep(2);
            }
        }
        __threadfence();   // acquire: invalidate L1/L2 before reading producers' data
    }
    __syncthreads();
}

// Per-batch softmax over depths + per-box affine params + pixel rect + compaction.
__device__ void box_params_dev(int b, const float* __restrict__ zwhere,
    const int* __restrict__ zpresent, const float* __restrict__ zdepth,
    float* wgt, float* sxs, float* oxs, float* sys, float* oys,
    int* binst, int* rect, int* cidx, int* bcnt, char* smemc)
{
    float* sd  = (float*)smemc;   // 512 slots (380 used)
    float* red = sd + 512;        // 256
    int tid = threadIdx.x;

    for (int n = tid; n < NBOX; n += 256) {
        int loc = loc_of_box(n);
        sd[n] = (zpresent[b * NBOX + n] == 1) ? zdepth[b * NLOCS + loc] : -1000.0f;
    }
    __syncthreads();

    float m = sd[tid];
    if (tid + 256 < NBOX) m = fmaxf(m, sd[tid + 256]);
    red[tid] = m; __syncthreads();
    for (int s = 128; s > 0; s >>= 1) {
        if (tid < s) red[tid] = fmaxf(red[tid], red[tid + s]);
        __syncthreads();
    }
    m = red[0]; __syncthreads();

    float sum = expf(sd[tid] - m);
    if (tid + 256 < NBOX) sum += expf(sd[tid + 256] - m);
    red[tid] = sum; __syncthreads();
    for (int s = 128; s > 0; s >>= 1) {
        if (tid < s) red[tid] += red[tid + s];
        __syncthreads();
    }
    float inv = 1.0f / red[0];
    __syncthreads();

    for (int n = tid; n < NBOX; n += 256) {
        int g = b * NBOX + n;
        float wv = expf(sd[n] - m) * inv;   // exp(-1000-m) underflows to exactly 0
        wgt[g] = wv;
        float cx = zwhere[g * 4 + 0], cy = zwhere[g * 4 + 1];
        float w  = zwhere[g * 4 + 2], h  = zwhere[g * 4 + 3];
        float isx = 1.0f / fmaxf(w, 1e-5f);
        float isy = 1.0f / fmaxf(h, 1e-5f);
        float sxv = isx * (63.0f / 127.0f);
        float oxv = 31.5f * (1.0f - 2.0f * cx * isx);
        float syv = isy * (63.0f / 127.0f);
        float oyv = 31.5f * (1.0f - 2.0f * cy * isy);
        sxs[g] = sxv; oxs[g] = oxv; sys[g] = syv; oys[g] = oyv;
        binst[g] = b * NLOCS + loc_of_box(n);
        int wlo = min(127, max(0, (int)floorf((-1.0f - oxv) / sxv)));
        int whi = max(0, min(127, (int)ceilf((64.0f - oxv) / sxv)));
        int hlo = min(127, max(0, (int)floorf((-1.0f - oyv) / syv)));
        int hhi = max(0, min(127, (int)ceilf((64.0f - oyv) / syv)));
        rect[g] = wlo | (whi << 8) | (hlo << 16) | (hhi << 24);
        sd[n] = wv;   // presence flag for compaction
    }
    __syncthreads();

    if (tid < 64) {   // wave 0: deterministic ascending compaction
        int base = 0;
        for (int c = 0; c < 6; ++c) {
            int n = c * 64 + tid;
            bool p = (n < NBOX) && (sd[n] > 0.0f);
            unsigned long long mask = __ballot(p);
            int pos = __popcll(mask & ((1ull << tid) - 1ull));
            if (p) cidx[b * NBOX + base + pos] = n;
            base += __popcll(mask);
        }
        if (tid == 0) bcnt[b] = base;
    }
}

// One deconv layer as SGEMM over grid-strided tiles.
// Y[M, 4*cout] = X[M,K] . W4[K, 4*cout]; W4[k][t*cout+co] = w[3-t][k][co].
// BM = 16*RPT, BN = 64, BK = 32; 256 threads (16x16), micro-tile RPT x 4.
template<int RPT>
__device__ void gemm_layer(const float* __restrict__ X, const float* __restrict__ Wt,
                           const float* __restrict__ bias, float* __restrict__ Y,
                           int M, int K, int coutsh, int sinsh, int act,
                           int mt, int nt, char* smemc)
{
    constexpr int BM = 16 * RPT;
    constexpr int TPR = 16 / RPT;      // threads per row (staging)
    constexpr int FPT = 2 * RPT;       // floats per thread along K (staging)
    constexpr int NQ = FPT / 4;        // float4s per thread (RPT=2 -> 1, RPT=4 -> 2)
    float (*Xs)[BM + 4] = (float (*)[BM + 4])smemc;
    float (*Ws)[64]     = (float (*)[64])(smemc + sizeof(float) * 32 * (BM + 4));
    const int cout = 1 << coutsh;
    const int sin = 1 << sinsh;
    const int s2sh = 2 * sinsh;
    const int tid = threadIdx.x, tx = tid & 15, ty = tid >> 4;
    const int srow = tid / TPR;
    const int skq  = (tid % TPR) * FPT;
    const int ntile = mt * nt;

    for (int t = blockIdx.x; t < ntile; t += NBLK) {
        const int mi = t % mt, ni = t / mt;
        const int mbase = mi * BM, nbase = ni * 64;
        const bool srow_ok = (mbase + srow) < M;
        const float* xb = X + (size_t)(mbase + srow) * K + skq;

        float acc[RPT][4];
        #pragma unroll
        for (int r = 0; r < RPT; ++r)
            #pragma unroll
            for (int c = 0; c < 4; ++c) acc[r][c] = 0.f;

        const int KC = K >> 5;
        for (int kc = 0; kc < KC; ++kc) {
            const int k0 = kc << 5;
            float4 xv[NQ];
            #pragma unroll
            for (int q = 0; q < NQ; ++q)
                xv[q] = srow_ok ? *(const float4*)(xb + k0 + 4 * q)
                                : make_float4(0.f, 0.f, 0.f, 0.f);
            #pragma unroll
            for (int q = 0; q < NQ; ++q) {
                Xs[skq + 4 * q + 0][srow] = xv[q].x;
                Xs[skq + 4 * q + 1][srow] = xv[q].y;
                Xs[skq + 4 * q + 2][srow] = xv[q].z;
                Xs[skq + 4 * q + 3][srow] = xv[q].w;
            }
            #pragma unroll
            for (int i2 = 0; i2 < 8; ++i2) {
                int idx = tid + i2 * 256;
                int kk = idx >> 6, nn = idx & 63;
                int col = nbase + nn;
                int tt = col >> coutsh, co = col & (cout - 1);
                Ws[kk][nn] = Wt[(size_t)(3 - tt) * K * cout + (size_t)(k0 + kk) * cout + co];
            }
            __syncthreads();

            #pragma unroll
            for (int kk = 0; kk < 32; ++kk) {
                float b4[4];
                *(float4*)b4 = *(const float4*)&Ws[kk][tx * 4];
                float a[RPT];
                if constexpr (RPT == 2) {
                    float2 t2 = *(const float2*)&Xs[kk][ty * 2];
                    a[0] = t2.x; a[1] = t2.y;
                } else {
                    #pragma unroll
                    for (int q = 0; q < RPT / 4; ++q) {
                        float4 t4 = *(const float4*)&Xs[kk][ty * RPT + 4 * q];
                        a[4 * q] = t4.x; a[4 * q + 1] = t4.y;
                        a[4 * q + 2] = t4.z; a[4 * q + 3] = t4.w;
                    }
                }
                #pragma unroll
                for (int r = 0; r < RPT; ++r)
                    #pragma unroll
                    for (int c = 0; c < 4; ++c)
                        acc[r][c] = fmaf(a[r], b4[c], acc[r][c]);
            }
            __syncthreads();
        }

        // epilogue: bias + activation + HWC scatter
        #pragma unroll
        for (int r = 0; r < RPT; ++r) {
            int row = mbase + ty * RPT + r;
            if (row >= M) continue;
            int inst = row >> s2sh;
            int p = row & ((1 << s2sh) - 1);
            int i = p >> sinsh, j = p & (sin - 1);
            size_t ybase = (size_t)inst << (s2sh + 2 + coutsh);
            #pragma unroll
            for (int c = 0; c < 4; ++c) {
                int col = nbase + tx * 4 + c;
                int tt = col >> coutsh, co = col & (cout - 1);
                int oy = 2 * i + (tt >> 1), ox = 2 * j + (tt & 1);
                float v = acc[r][c] + bias[co];
                v = act ? (1.0f / (1.0f + expf(-v))) : fmaxf(v, 0.f);
                Y[ybase + ((((size_t)oy << (sinsh + 1)) + ox) << coutsh) + co] = v;
            }
        }
    }
}

// Last layer (cin=16, cout=3): grid-strided tasks of 64 cells x 4 taps.
__device__ void last_layer(const float* __restrict__ X, const float* __restrict__ Wt,
                           const float* __restrict__ bias, float* __restrict__ dec)
{
    int lane = threadIdx.x & 63;
    int wv = __builtin_amdgcn_readfirstlane((int)(threadIdx.x >> 6)); // 0..3
    int di = wv >> 1, dj = wv & 1;
    const float* wp = Wt + (3 - (2 * di + dj)) * 48;   // [k][co] 16x3, tap-flipped
    float b0 = bias[0], b1 = bias[1], b2 = bias[2];

    for (int task = blockIdx.x; task < 5440; task += NBLK) {
        int cell = task * 64 + lane;            // < 348160 = NINST*32*32
        int inst = cell >> 10, rc2 = cell & 1023;
        int i = rc2 >> 5, j = rc2 & 31;

        const float* xp = X + (size_t)cell * 16;
        float4 x0 = *(const float4*)xp;
        float4 x1 = *(const float4*)(xp + 4);
        float4 x2 = *(const float4*)(xp + 8);
        float4 x3 = *(const float4*)(xp + 12);
        float xk[16] = {x0.x,x0.y,x0.z,x0.w, x1.x,x1.y,x1.z,x1.w,
                        x2.x,x2.y,x2.z,x2.w, x3.x,x3.y,x3.z,x3.w};

        float c0 = b0, c1 = b1, c2 = b2;
        #pragma unroll
        for (int k = 0; k < 16; ++k) {
            c0 = fmaf(xk[k], wp[k * 3 + 0], c0);
            c1 = fmaf(xk[k], wp[k * 3 + 1], c1);
            c2 = fmaf(xk[k], wp[k * 3 + 2], c2);
        }
        c0 = 1.0f / (1.0f + expf(-c0));
        c1 = 1.0f / (1.0f + expf(-c1));
        c2 = 1.0f / (1.0f + expf(-c2));

        int oy = 2 * i + di, ox = 2 * j + dj;
        float* dp = dec + (size_t)inst * 12288 + (size_t)(oy * 64 + ox) * 3;
        dp[0] = c0; dp[1] = c1; dp[2] = c2;
    }
}

// STN bilinear + weighted partial composite. block = (s in 0..2, b, 16x16 tile).
__device__ void composite_dev(const float* __restrict__ dec, const float* wgt,
    const float* sxs, const float* oxs, const float* sys, const float* oys,
    const int* binst, const int* rect, const int* cidx, const int* bcnt,
    float* __restrict__ part, char* smemc)
{
    float* s_w  = (float*)smemc;
    float* s_sx = s_w + NBOX;  float* s_ox = s_sx + NBOX;
    float* s_sy = s_ox + NBOX; float* s_oy = s_sy + NBOX;
    int* s_i  = (int*)(s_oy + NBOX);
    int* s_r  = s_i + NBOX;
    int* s_ci = s_r + NBOX;

    int bid = blockIdx.x;
    int s = bid >> 8;            // 0..2
    int rem = bid & 255;
    int b = rem >> 6, tile = rem & 63;
    int tx0 = (tile & 7) << 4, ty0 = (tile >> 3) << 4;

    for (int n = threadIdx.x; n < NBOX; n += 256) {
        int g = b * NBOX + n;
        s_w[n] = wgt[g]; s_sx[n] = sxs[g]; s_ox[n] = oxs[g];
        s_sy[n] = sys[g]; s_oy[n] = oys[g]; s_i[n] = binst[g];
        s_r[n] = rect[g]; s_ci[n] = cidx[g];
    }
    __syncthreads();

    int nb = bcnt[b];
    int lo = (nb * s) / 3, hi = (nb * (s + 1)) / 3;
    int lx = threadIdx.x & 15, ly = threadIdx.x >> 4;
    int w = tx0 + lx, h = ty0 + ly;
    float fw = (float)w, fh = (float)h;
    float a0 = 0.f, a1 = 0.f, a2 = 0.f;

    for (int q = lo; q < hi; ++q) {
        int n = s_ci[q];
        int rc = s_r[n];
        int wlo = rc & 255, whi = (rc >> 8) & 255;
        int hlo = (rc >> 16) & 255, hhi = (rc >> 24) & 255;
        if (whi < tx0 || wlo > tx0 + 15 || hhi < ty0 || hlo > ty0 + 15) continue;
        float wg = s_w[n];
        float px = fmaf(fw, s_sx[n], s_ox[n]);
        float py = fmaf(fh, s_sy[n], s_oy[n]);
        float x0 = floorf(px), y0 = floorf(py);
        if (x0 < -1.0f || x0 > 63.0f || y0 < -1.0f || y0 > 63.0f) continue;
        float wx = px - x0, wy = py - y0;
        int ix = (int)x0, iy = (int)y0;
        int x0c = max(ix, 0), x1c = min(ix + 1, 63);
        int y0c = max(iy, 0), y1c = min(iy + 1, 63);
        float m00 = (ix >= 0 && iy >= 0) ? 1.f : 0.f;
        float m01 = (ix + 1 <= 63 && iy >= 0) ? 1.f : 0.f;
        float m10 = (ix >= 0 && iy + 1 <= 63) ? 1.f : 0.f;
        float m11 = (ix + 1 <= 63 && iy + 1 <= 63) ? 1.f : 0.f;
        float w00 = (1.f - wy) * (1.f - wx) * m00;
        float w01 = (1.f - wy) * wx * m01;
        float w10 = wy * (1.f - wx) * m10;
        float w11 = wy * wx * m11;
        const float* img = dec + (size_t)s_i[n] * 12288;   // (64,64,3) HWC
        int b00 = (y0c * 64 + x0c) * 3, b01 = (y0c * 64 + x1c) * 3;
        int b10 = (y1c * 64 + x0c) * 3, b11 = (y1c * 64 + x1c) * 3;
        a0 += wg * (w00 * img[b00]   + w01 * img[b01]   + w10 * img[b10]   + w11 * img[b11]);
        a1 += wg * (w00 * img[b00+1] + w01 * img[b01+1] + w10 * img[b10+1] + w11 * img[b11+1]);
        a2 += wg * (w00 * img[b00+2] + w01 * img[b01+2] + w10 * img[b10+2] + w11 * img[b11+2]);
    }
    size_t pb = (size_t)s * 196608 + (size_t)(b * 3) * 16384 + (size_t)h * 128 + w;
    part[pb]         = a0;
    part[pb + 16384] = a1;
    part[pb + 32768] = a2;
}

__global__ __launch_bounds__(256, 4) void mega_k(
    const float* __restrict__ z_what, const float* __restrict__ z_where,
    const int* __restrict__ z_present, const float* __restrict__ z_depth,
    const float* __restrict__ W0, const float* __restrict__ Bs0,
    const float* __restrict__ W1, const float* __restrict__ Bs1,
    const float* __restrict__ W2, const float* __restrict__ Bs2,
    const float* __restrict__ W3, const float* __restrict__ Bs3,
    const float* __restrict__ W4, const float* __restrict__ Bs4,
    const float* __restrict__ W5, const float* __restrict__ Bs5,
    float* __restrict__ out, char* __restrict__ ws)
{
    __shared__ __align__(16) char smem[16896];

    float* A     = (float*)ws;                      // 22.3 MB max (L4 out)
    float* Bbuf  = (float*)(ws + (24u << 20));      // 16.7 MB max (dec)
    float* Cpart = (float*)(ws + (44u << 20));      // 2.36 MB partials
    float* P     = (float*)(ws + (47u << 20));
    float* wgt = P;            float* sxs = P + 1520;   float* oxs = P + 2 * 1520;
    float* sys = P + 3 * 1520; float* oys = P + 4 * 1520;
    int* binst = (int*)(P + 5 * 1520);
    int* rect  = binst + 1520;
    int* cidx  = binst + 2 * 1520;
    int* bcnt  = binst + 3 * 1520;
    int* cnts  = bcnt + 4;
    unsigned* gens = (unsigned*)(cnts + 8);
    unsigned* flag = gens + 8;

    // one-time (poison-proof) init of barrier counters
    if (threadIdx.x == 0) {
        if (blockIdx.x == 0) {
            if (__hip_atomic_load(flag, __ATOMIC_SEQ_CST, __HIP_MEMORY_SCOPE_AGENT) != GOLDEN) {
                for (int i = 0; i < 8; ++i)
                    __hip_atomic_store(&cnts[i], 0, __ATOMIC_RELAXED, __HIP_MEMORY_SCOPE_AGENT);
                __threadfence();
                __hip_atomic_store(flag, GOLDEN, __ATOMIC_SEQ_CST, __HIP_MEMORY_SCOPE_AGENT);
            }
        } else {
            while (__hip_atomic_load(flag, __ATOMIC_SEQ_CST, __HIP_MEMORY_SCOPE_AGENT) != GOLDEN) {
                __builtin_amdgcn_s_sleep(2);
            }
        }
    }
    __syncthreads();

    // Phase A: box params (blocks 704-707) || L0 GEMM (tiles 0..175)
    if (blockIdx.x >= 704 && blockIdx.x < 708)
        box_params_dev(blockIdx.x - 704, z_where, z_present, z_depth,
                       wgt, sxs, oxs, sys, oys, binst, rect, cidx, bcnt, smem);
    gemm_layer<2>(z_what, W0, Bs0, A,    340,    64, 8, 0, 0, 11,  16, smem);
    grid_bar(&cnts[0], &gens[0]);
    gemm_layer<2>(A,      W1, Bs1, Bbuf, 1360,  256, 7, 1, 0, 43,   8, smem);
    grid_bar(&cnts[1], &gens[1]);
    gemm_layer<4>(Bbuf,   W2, Bs2, A,    5440,  128, 6, 2, 0, 85,   4, smem);
    grid_bar(&cnts[2], &gens[2]);
    gemm_layer<4>(A,      W3, Bs3, Bbuf, 21760,  64, 5, 3, 0, 340,  2, smem);
    grid_bar(&cnts[3], &gens[3]);
    gemm_layer<4>(Bbuf,   W4, Bs4, A,    87040,  32, 4, 4, 0, 1360, 1, smem);
    grid_bar(&cnts[4], &gens[4]);
    last_layer(A, W5, Bs5, Bbuf);
    grid_bar(&cnts[5], &gens[5]);
    composite_dev(Bbuf, wgt, sxs, oxs, sys, oys, binst, rect, cidx, bcnt, Cpart, smem);
    grid_bar(&cnts[6], &gens[6]);
    // reduce: 768*256 threads == 196608 outputs exactly
    int gt = blockIdx.x * 256 + threadIdx.x;
    out[gt] = Cpart[gt] + Cpart[gt + 196608] + Cpart[gt + 2 * 196608];
}

extern "C" void kernel_launch(void* const* d_in, const int* in_sizes, int n_in,
                              void* d_out, int out_size, void* d_ws, size_t ws_size,
                              hipStream_t stream)
{
    const float* z_what    = (const float*)d_in[0];
    const float* z_where   = (const float*)d_in[1];
    const int*   z_present = (const int*)  d_in[2];
    const float* z_depth   = (const float*)d_in[3];

    mega_k<<<dim3(NBLK), dim3(256), 0, stream>>>(
        z_what, z_where, z_present, z_depth,
        (const float*)d_in[4],  (const float*)d_in[5],
        (const float*)d_in[6],  (const float*)d_in[7],
        (const float*)d_in[8],  (const float*)d_in[9],
        (const float*)d_in[10], (const float*)d_in[11],
        (const float*)d_in[12], (const float*)d_in[13],
        (const float*)d_in[14], (const float*)d_in[15],
        (float*)d_out, (char*)d_ws);
}

// Round 6
// 99.320 us; speedup vs baseline: 12.4182x; 12.4182x over previous
//
#include <hip/hip_runtime.h>
#include <hip/hip_bf16.h>

#define NBOX  380
#define NLOCS 85
#define NINST 340   // B(4) * NLOCS(85)
#define NSPLIT 8

// box index -> location index (from _recon_indices structure)
__device__ __forceinline__ int loc_of_box(int n) {
    if (n < 256) return n >> 2;               // fm=8, 4 boxes/loc
    if (n < 352) return 64 + (n - 256) / 6;   // fm=4, 6 boxes/loc
    if (n < 376) return 80 + (n - 352) / 6;   // fm=2, 6 boxes/loc
    return 84;                                // fm=1, 4 boxes/loc
}

// Per-batch softmax over depths + per-box affine params + pixel rect + compaction.
__global__ void box_params_k(const float* __restrict__ zwhere,
                             const int* __restrict__ zpresent,
                             const float* __restrict__ zdepth,
                             float* __restrict__ wgt, float* __restrict__ sxs,
                             float* __restrict__ oxs, float* __restrict__ sys,
                             float* __restrict__ oys, int* __restrict__ binst,
                             int* __restrict__ rect, int* __restrict__ cidx,
                             int* __restrict__ cnt)
{
    int b = blockIdx.x;
    int tid = threadIdx.x;            // 128 threads
    __shared__ float sd[NBOX];
    __shared__ float red[128];

    for (int n = tid; n < NBOX; n += 128) {
        int loc = loc_of_box(n);
        sd[n] = (zpresent[b * NBOX + n] == 1) ? zdepth[b * NLOCS + loc] : -1000.0f;
    }
    __syncthreads();

    float m = -1e30f;
    for (int n = tid; n < NBOX; n += 128) m = fmaxf(m, sd[n]);
    red[tid] = m; __syncthreads();
    for (int s = 64; s > 0; s >>= 1) {
        if (tid < s) red[tid] = fmaxf(red[tid], red[tid + s]);
        __syncthreads();
    }
    m = red[0]; __syncthreads();

    float sum = 0.0f;
    for (int n = tid; n < NBOX; n += 128) sum += expf(sd[n] - m);
    red[tid] = sum; __syncthreads();
    for (int s = 64; s > 0; s >>= 1) {
        if (tid < s) red[tid] += red[tid + s];
        __syncthreads();
    }
    float inv = 1.0f / red[0];
    __syncthreads();

    for (int n = tid; n < NBOX; n += 128) {
        int g = b * NBOX + n;
        float wv = expf(sd[n] - m) * inv;   // exp(-1000-m) underflows to exactly 0
        wgt[g] = wv;
        float cx = zwhere[g * 4 + 0], cy = zwhere[g * 4 + 1];
        float w  = zwhere[g * 4 + 2], h  = zwhere[g * 4 + 3];
        float isx = 1.0f / fmaxf(w, 1e-5f);
        float isy = 1.0f / fmaxf(h, 1e-5f);
        float sxv = isx * (63.0f / 127.0f);
        float oxv = 31.5f * (1.0f - 2.0f * cx * isx);
        float syv = isy * (63.0f / 127.0f);
        float oyv = 31.5f * (1.0f - 2.0f * cy * isy);
        sxs[g] = sxv; oxs[g] = oxv; sys[g] = syv; oys[g] = oyv;
        binst[g] = b * NLOCS + loc_of_box(n);
        int wlo = min(127, max(0, (int)floorf((-1.0f - oxv) / sxv)));
        int whi = max(0, min(127, (int)ceilf((64.0f - oxv) / sxv)));
        int hlo = min(127, max(0, (int)floorf((-1.0f - oyv) / syv)));
        int hhi = max(0, min(127, (int)ceilf((64.0f - oyv) / syv)));
        rect[g] = wlo | (whi << 8) | (hlo << 16) | (hhi << 24);
        sd[n] = wv;   // presence flag for compaction
    }
    __syncthreads();

    if (tid < 64) {   // wave 0: deterministic ascending compaction
        int base = 0;
        for (int c = 0; c < 6; ++c) {
            int n = c * 64 + tid;
            bool p = (n < NBOX) && (sd[n] > 0.0f);
            unsigned long long mask = __ballot(p);
            int pos = __popcll(mask & ((1ull << tid) - 1ull));
            if (p) cidx[b * NBOX + base + pos] = n;
            base += __popcll(mask);
        }
        if (tid == 0) cnt[b] = base;
    }
}

// Whole decoder (L0..L5) for ONE instance per block, activations in LDS.
// Layer out[(2i+di, 2j+dj)][co] = relu/sig( b[co] + sum_k x[(i,j)][k] * W[1-di][1-dj][k][co] )
// tap t = 2di+dj, flipped index ft = 3-t.
__global__ __launch_bounds__(256) void decode_fused_k(
    const float* __restrict__ z_what,
    const float* __restrict__ W0, const float* __restrict__ B0,
    const float* __restrict__ W1, const float* __restrict__ B1,
    const float* __restrict__ W2, const float* __restrict__ B2,
    const float* __restrict__ W3, const float* __restrict__ B3,
    const float* __restrict__ W4, const float* __restrict__ B4,
    const float* __restrict__ W5, const float* __restrict__ B5,
    float* __restrict__ dec)
{
    __shared__ __align__(16) float sm[15552];   // 62,208 B
    float* s_x = sm;            // [64] z_what
    float* L0o = sm + 64;       // [4 px][256 co]
    float* L1o = sm + 1088;     // [16 px][128 co]
    float* L2o = sm + 3136;     // [64 ch][66]  (64 px + 2 pad)
    float* L4b = sm + 3136;     // [16 ch][258] overlay (L2o dead after L3)
    float* L3o = sm + 7360;     // [32 ch][256 px]

    const int inst = blockIdx.x;
    const int tid = threadIdx.x;
    const int lane = tid & 63;
    const int wv = __builtin_amdgcn_readfirstlane(tid >> 6);   // wave id 0..3

    if (tid < 64) s_x[tid] = z_what[inst * 64 + tid];
    __syncthreads();

    // ---- L0: K=64 -> cout=256, 1px -> 2x2.  lane = co.
    {
        float a0 = 0.f, a1 = 0.f, a2 = 0.f, a3 = 0.f;
        #pragma unroll 8
        for (int k = 0; k < 64; ++k) {
            float xv = s_x[k];
            a0 = fmaf(xv, W0[(3 * 64 + k) * 256 + tid], a0);   // t=0, ft=3
            a1 = fmaf(xv, W0[(2 * 64 + k) * 256 + tid], a1);   // t=1, ft=2
            a2 = fmaf(xv, W0[(1 * 64 + k) * 256 + tid], a2);   // t=2, ft=1
            a3 = fmaf(xv, W0[(0 * 64 + k) * 256 + tid], a3);   // t=3, ft=0
        }
        float bb = B0[tid];
        L0o[0 * 256 + tid] = fmaxf(a0 + bb, 0.f);   // out px = t
        L0o[1 * 256 + tid] = fmaxf(a1 + bb, 0.f);
        L0o[2 * 256 + tid] = fmaxf(a2 + bb, 0.f);
        L0o[3 * 256 + tid] = fmaxf(a3 + bb, 0.f);
    }
    __syncthreads();

    // ---- L1: K=256 -> cout=128, 2x2 -> 4x4.  lane = co (128), tap-half th = tid>>7.
    {
        const int co = tid & 127;
        const int th = __builtin_amdgcn_readfirstlane(tid >> 7);  // di = th, dj = s
        const int ftA = 3 - 2 * th;   // s=0
        const int ftB = 2 - 2 * th;   // s=1
        float accA[4] = {0.f, 0.f, 0.f, 0.f};
        float accB[4] = {0.f, 0.f, 0.f, 0.f};
        #pragma unroll 2
        for (int q = 0; q < 64; ++q) {
            int k0 = q * 4;
            float xr[4][4];
            *(float4*)xr[0] = *(const float4*)&L0o[0 * 256 + k0];
            *(float4*)xr[1] = *(const float4*)&L0o[1 * 256 + k0];
            *(float4*)xr[2] = *(const float4*)&L0o[2 * 256 + k0];
            *(float4*)xr[3] = *(const float4*)&L0o[3 * 256 + k0];
            #pragma unroll
            for (int kk = 0; kk < 4; ++kk) {
                int k = k0 + kk;
                float wA = W1[(ftA * 256 + k) * 128 + co];
                float wB = W1[(ftB * 256 + k) * 128 + co];
                #pragma unroll
                for (int p = 0; p < 4; ++p) {
                    accA[p] = fmaf(xr[p][kk], wA, accA[p]);
                    accB[p] = fmaf(xr[p][kk], wB, accB[p]);
                }
            }
        }
        float bb = B1[co];
        #pragma unroll
        for (int p = 0; p < 4; ++p) {
            int i = p >> 1, j = p & 1;
            int opb = (2 * i + th) * 4 + 2 * j;
            L1o[(opb + 0) * 128 + co] = fmaxf(accA[p] + bb, 0.f);
            L1o[(opb + 1) * 128 + co] = fmaxf(accB[p] + bb, 0.f);
        }
    }
    __syncthreads();

    // ---- L2: K=128 -> cout=64, 4x4 -> 8x8.  lane = co (64), wave = tap.
    {
        const int co = tid & 63;
        const int t = wv, ft = 3 - t, di = t >> 1, dj = t & 1;
        float acc[16];
        #pragma unroll
        for (int p = 0; p < 16; ++p) acc[p] = 0.f;
        #pragma unroll 2
        for (int q = 0; q < 32; ++q) {
            int k0 = q * 4;
            float wk[4];
            #pragma unroll
            for (int kk = 0; kk < 4; ++kk)
                wk[kk] = W2[(ft * 128 + k0 + kk) * 64 + co];
            #pragma unroll
            for (int p = 0; p < 16; ++p) {
                float4 xq = *(const float4*)&L1o[p * 128 + k0];
                acc[p] = fmaf(xq.x, wk[0], acc[p]);
                acc[p] = fmaf(xq.y, wk[1], acc[p]);
                acc[p] = fmaf(xq.z, wk[2], acc[p]);
                acc[p] = fmaf(xq.w, wk[3], acc[p]);
            }
        }
        float bb = B2[co];
        #pragma unroll
        for (int p = 0; p < 16; ++p) {
            int i = p >> 2, j = p & 3;
            int op = (2 * i + di) * 8 + 2 * j + dj;
            L2o[co * 66 + op] = fmaxf(acc[p] + bb, 0.f);
        }
    }
    __syncthreads();

    // ---- L3: K=64 -> cout=32, 8x8 -> 16x16.  lane = px (64), wave = (di, co-half).
    {
        const int di = wv >> 1, coh = wv & 1;
        const int ft0 = 3 - 2 * di, ft1 = 2 - 2 * di;   // dj = 0 / 1
        float a0[16], a1[16];
        #pragma unroll
        for (int c = 0; c < 16; ++c) { a0[c] = 0.f; a1[c] = 0.f; }
        #pragma unroll 2
        for (int k = 0; k < 64; ++k) {
            float xv = L2o[k * 66 + lane];
            const float* w0p = W3 + (ft0 * 64 + k) * 32 + coh * 16;
            const float* w1p = W3 + (ft1 * 64 + k) * 32 + coh * 16;
            #pragma unroll
            for (int c = 0; c < 16; ++c) {
                a0[c] = fmaf(xv, w0p[c], a0[c]);
                a1[c] = fmaf(xv, w1p[c], a1[c]);
            }
        }
        int i = lane >> 3, j = lane & 7;
        #pragma unroll
        for (int c = 0; c < 16; ++c) {
            float bb = B3[coh * 16 + c];
            float2 v = make_float2(fmaxf(a0[c] + bb, 0.f), fmaxf(a1[c] + bb, 0.f));
            *(float2*)&L3o[(coh * 16 + c) * 256 + (2 * i + di) * 16 + 2 * j] = v;
        }
    }
    __syncthreads();

    // ---- L4 (K=32 -> 16, 16x16 -> 32x32) + L5 (K=16 -> 3, sigmoid) fused in 4 chunks.
    // Preload L5 weights/bias (wave = tap for L5) -> scalar regs.
    const int t5 = wv, ft5 = 3 - t5, di5 = t5 >> 1, dj5 = t5 & 1;
    float w5r[16][3];
    #pragma unroll
    for (int k = 0; k < 16; ++k)
        #pragma unroll
        for (int c = 0; c < 3; ++c)
            w5r[k][c] = W5[(ft5 * 16 + k) * 3 + c];
    const float b50 = B5[0], b51 = B5[1], b52 = B5[2];

    for (int c4 = 0; c4 < 4; ++c4) {
        {   // L4 on input rows 4*c4 .. 4*c4+3; lane = (il,j), wave = (di, co-half)
            const int di = wv >> 1, coh = wv & 1;
            const int ft0 = 3 - 2 * di, ft1 = 2 - 2 * di;
            float a0[8], a1[8];
            #pragma unroll
            for (int c = 0; c < 8; ++c) { a0[c] = 0.f; a1[c] = 0.f; }
            #pragma unroll 4
            for (int k = 0; k < 32; ++k) {
                float xv = L3o[k * 256 + 64 * c4 + lane];
                const float* w0p = W4 + (ft0 * 32 + k) * 16 + coh * 8;
                const float* w1p = W4 + (ft1 * 32 + k) * 16 + coh * 8;
                #pragma unroll
                for (int c = 0; c < 8; ++c) {
                    a0[c] = fmaf(xv, w0p[c], a0[c]);
                    a1[c] = fmaf(xv, w1p[c], a1[c]);
                }
            }
            int il = lane >> 4, j = lane & 15;
            #pragma unroll
            for (int c = 0; c < 8; ++c) {
                float bb = B4[coh * 8 + c];
                float2 v = make_float2(fmaxf(a0[c] + bb, 0.f), fmaxf(a1[c] + bb, 0.f));
                *(float2*)&L4b[(coh * 8 + c) * 258 + (2 * il + di) * 32 + 2 * j] = v;
            }
        }
        __syncthreads();
        {   // L5 on this chunk's 256 L4-output px (local rows 0..7 = global 8*c4..)
            #pragma unroll
            for (int sub = 0; sub < 4; ++sub) {
                int pl = sub * 64 + lane;
                int r = pl >> 5, x5 = pl & 31;
                int y5 = 8 * c4 + r;
                float a0 = b50, a1 = b51, a2 = b52;
                #pragma unroll
                for (int k = 0; k < 16; ++k) {
                    float xv = L4b[k * 258 + pl];
                    a0 = fmaf(xv, w5r[k][0], a0);
                    a1 = fmaf(xv, w5r[k][1], a1);
                    a2 = fmaf(xv, w5r[k][2], a2);
                }
                a0 = 1.0f / (1.0f + expf(-a0));
                a1 = 1.0f / (1.0f + expf(-a1));
                a2 = 1.0f / (1.0f + expf(-a2));
                float* dp = dec + (size_t)inst * 12288
                          + (size_t)((2 * y5 + di5) * 64 + 2 * x5 + dj5) * 3;
                dp[0] = a0; dp[1] = a1; dp[2] = a2;
            }
        }
        __syncthreads();
    }
}

// Fused STN bilinear sample + weighted partial composite.
__global__ __launch_bounds__(256) void composite_k(
    const float* __restrict__ dec, const float* __restrict__ wgt,
    const float* __restrict__ sxs, const float* __restrict__ oxs,
    const float* __restrict__ sys, const float* __restrict__ oys,
    const int* __restrict__ binst, const int* __restrict__ rect,
    const int* __restrict__ cidx, const int* __restrict__ cnt,
    float* __restrict__ part)
{
    int b = blockIdx.z, s = blockIdx.y;
    int tx0 = (blockIdx.x & 7) << 4, ty0 = (blockIdx.x >> 3) << 4;
    int lx = threadIdx.x & 15, ly = threadIdx.x >> 4;
    int w = tx0 + lx, h = ty0 + ly;

    int nb = cnt[b];
    int lo = (nb * s) / NSPLIT, hi = (nb * (s + 1)) / NSPLIT;

    float fw = (float)w, fh = (float)h;
    float a0 = 0.f, a1 = 0.f, a2 = 0.f;
    for (int q = lo; q < hi; ++q) {
        int n = cidx[b * NBOX + q];
        int rc = rect[b * NBOX + n];
        int wlo = rc & 255, whi = (rc >> 8) & 255;
        int hlo = (rc >> 16) & 255, hhi = (rc >> 24) & 255;
        if (whi < tx0 || wlo > tx0 + 15 || hhi < ty0 || hlo > ty0 + 15) continue;
        int g = b * NBOX + n;
        float wg = wgt[g];
        float px = fmaf(fw, sxs[g], oxs[g]);
        float py = fmaf(fh, sys[g], oys[g]);
        float x0 = floorf(px), y0 = floorf(py);
        if (x0 < -1.0f || x0 > 63.0f || y0 < -1.0f || y0 > 63.0f) continue;
        float wx = px - x0, wy = py - y0;
        int ix = (int)x0, iy = (int)y0;
        int x0c = max(ix, 0), x1c = min(ix + 1, 63);
        int y0c = max(iy, 0), y1c = min(iy + 1, 63);
        float m00 = (ix >= 0 && iy >= 0) ? 1.f : 0.f;
        float m01 = (ix + 1 <= 63 && iy >= 0) ? 1.f : 0.f;
        float m10 = (ix >= 0 && iy + 1 <= 63) ? 1.f : 0.f;
        float m11 = (ix + 1 <= 63 && iy + 1 <= 63) ? 1.f : 0.f;
        float w00 = (1.f - wy) * (1.f - wx) * m00;
        float w01 = (1.f - wy) * wx * m01;
        float w10 = wy * (1.f - wx) * m10;
        float w11 = wy * wx * m11;
        const float* img = dec + (size_t)binst[g] * 12288;   // (64,64,3) HWC
        int b00 = (y0c * 64 + x0c) * 3, b01 = (y0c * 64 + x1c) * 3;
        int b10 = (y1c * 64 + x0c) * 3, b11 = (y1c * 64 + x1c) * 3;
        a0 += wg * (w00 * img[b00]   + w01 * img[b01]   + w10 * img[b10]   + w11 * img[b11]);
        a1 += wg * (w00 * img[b00+1] + w01 * img[b01+1] + w10 * img[b10+1] + w11 * img[b11+1]);
        a2 += wg * (w00 * img[b00+2] + w01 * img[b01+2] + w10 * img[b10+2] + w11 * img[b11+2]);
    }
    size_t pb = (size_t)(b * NSPLIT + s) * 49152 + (size_t)h * 128 + w;
    part[pb]         = a0;
    part[pb + 16384] = a1;
    part[pb + 32768] = a2;
}

__global__ void reduce_k(const float* __restrict__ part, float* __restrict__ out)
{
    int i = blockIdx.x * 256 + threadIdx.x;   // < 196608
    int b = i / 49152;
    int r = i - b * 49152;
    float v = 0.f;
    #pragma unroll
    for (int s = 0; s < NSPLIT; ++s) v += part[(size_t)(b * NSPLIT + s) * 49152 + r];
    out[i] = v;
}

extern "C" void kernel_launch(void* const* d_in, const int* in_sizes, int n_in,
                              void* d_out, int out_size, void* d_ws, size_t ws_size,
                              hipStream_t stream)
{
    const float* z_what    = (const float*)d_in[0];   // (4,85,64)
    const float* z_where   = (const float*)d_in[1];   // (4,380,4)
    const int*   z_present = (const int*)  d_in[2];   // (4,380,1)
    const float* z_depth   = (const float*)d_in[3];   // (4,85,1)

    // workspace: dec 16.71 MB | part 6.29 MB | params ~55 KB
    char* ws = (char*)d_ws;
    float* dec  = (float*)ws;                           // 340*12288 f32
    float* part = (float*)(ws + 16711680);              // 4*8*49152 f32
    float* P    = (float*)(ws + 23003136);
    float* wgt = P,        *sxs = P + 1520, *oxs = P + 2 * 1520;
    float* sys = P + 3 * 1520, *oys = P + 4 * 1520;
    int* binst = (int*)(P + 5 * 1520);
    int* rect  = binst + 1520;
    int* cidx  = binst + 2 * 1520;
    int* cnt   = binst + 3 * 1520;

    box_params_k<<<dim3(4), dim3(128), 0, stream>>>(z_where, z_present, z_depth,
        wgt, sxs, oxs, sys, oys, binst, rect, cidx, cnt);

    decode_fused_k<<<dim3(NINST), dim3(256), 0, stream>>>(
        z_what,
        (const float*)d_in[4],  (const float*)d_in[5],
        (const float*)d_in[6],  (const float*)d_in[7],
        (const float*)d_in[8],  (const float*)d_in[9],
        (const float*)d_in[10], (const float*)d_in[11],
        (const float*)d_in[12], (const float*)d_in[13],
        (const float*)d_in[14], (const float*)d_in[15],
        dec);

    composite_k<<<dim3(64, NSPLIT, 4), dim3(256), 0, stream>>>(
        dec, wgt, sxs, oxs, sys, oys, binst, rect, cidx, cnt, part);
    reduce_k<<<dim3(768), dim3(256), 0, stream>>>(part, (float*)d_out);
}